// Round 4
// baseline (241.389 us; speedup 1.0000x reference)
//
#include <hip/hip_runtime.h>
#include <cstdint>
#include <cstddef>

typedef int int32x4  __attribute__((ext_vector_type(4)));
typedef int int32x16 __attribute__((ext_vector_type(16)));

#define AS1 __attribute__((address_space(1)))
#define AS3 __attribute__((address_space(3)))

__device__ __forceinline__ void gload_lds16(const void* g, void* l) {
    __builtin_amdgcn_global_load_lds((const AS1 void*)g, (AS3 void*)l, 16, 0, 0);
}

#define MFMA_I8(a, b, c) __builtin_amdgcn_mfma_i32_32x32x32_i8((a), (b), (c), 0, 0, 0)

// ---------------------------------------------------------------------------
// Fused quant kernel (frozen, round-3 version): blocks [0,4096) x-rows,
// [4096,8192) y-tiles.
// ---------------------------------------------------------------------------
__global__ __launch_bounds__(256) void quant_xy(const float* __restrict__ x,
                                                const float* __restrict__ y,
                                                signed char* __restrict__ A8,
                                                signed char* __restrict__ B8T,
                                                int* __restrict__ rs,
                                                int* __restrict__ sy) {
    const int t = threadIdx.x;
    if (blockIdx.x < 4096) {
        const int row = blockIdx.x;
        const float4* xr = (const float4*)(x + (size_t)row * 4096);
        char4* ar = (char4*)(A8 + (size_t)row * 4096);
        int s = 0;
#pragma unroll
        for (int i = 0; i < 4; i++) {
            const int idx = i * 256 + t;
            float4 v = xr[idx];
            int a0 = (int)v.x, a1 = (int)v.y, a2 = (int)v.z, a3 = (int)v.w;
            s += a0 + a1 + a2 + a3;
            char4 c;
            c.x = (signed char)a0; c.y = (signed char)a1;
            c.z = (signed char)a2; c.w = (signed char)a3;
            ar[idx] = c;
        }
#pragma unroll
        for (int off = 32; off > 0; off >>= 1) s += __shfl_down(s, off);
        __shared__ int wsum[4];
        if ((t & 63) == 0) wsum[t >> 6] = s;
        __syncthreads();
        if (t == 0) rs[row] = wsum[0] + wsum[1] + wsum[2] + wsum[3];
    } else {
        const int q = blockIdx.x - 4096;
        __shared__ int tile[64 * 17];
        __shared__ int ssum[64];
        const int nt = (q & 63) * 64;
        const int kt = (q >> 6) * 64;
        if (t < 64) ssum[t] = 0;
        __syncthreads();

        const int n4 = (t & 15) * 4;
        const int kb = (t >> 4) * 4;
        int b[4][4];
#pragma unroll
        for (int i = 0; i < 4; i++) {
            float4 v = *(const float4*)(y + (size_t)(kt + kb + i) * 4096 + nt + n4);
            b[i][0] = (int)v.x - 128; b[i][1] = (int)v.y - 128;
            b[i][2] = (int)v.z - 128; b[i][3] = (int)v.w - 128;
        }
#pragma unroll
        for (int j = 0; j < 4; j++) {
            const int s = b[0][j] + b[1][j] + b[2][j] + b[3][j];
            const int w = (b[0][j] & 255) | ((b[1][j] & 255) << 8) |
                          ((b[2][j] & 255) << 16) | (b[3][j] << 24);
            tile[(n4 + j) * 17 + (kb >> 2)] = w;
            atomicAdd(&ssum[n4 + j], s);
        }
        __syncthreads();

        const int n = t >> 2;
        const int kq = (t & 3) * 4;
        int32x4 o;
        o.x = tile[n * 17 + kq + 0];
        o.y = tile[n * 17 + kq + 1];
        o.z = tile[n * 17 + kq + 2];
        o.w = tile[n * 17 + kq + 3];
        *(int32x4*)(B8T + (size_t)(nt + n) * 4096 + kt + kq * 4) = o;
        if (t < 64) atomicAdd(&sy[nt + t], ssum[t]);
    }
}

// ---------------------------------------------------------------------------
// Kernel 3: int8 GEMM — REGISTER-PIPELINED round.
// Diagnosis (r0-r3): three different schedules all -> MfmaUtil 34%, because
// every MFMA cluster waits barrier+lgkmcnt(0) on frags loaded in the SAME
// phase: CU-wide LDS burst (~1200-1500cy, matrix pipe idle) alternates with
// MFMA burst (586cy/SIMD). Tile = ~3150cy vs 1171cy of MFMA work = 34%.
// Fix: cross-tile REGISTER double-buffering of fragments. Frags for
// half-tile h+1 are ds_read WHILE the MFMAs of half h run (reads hide under
// the 293cy cluster). MFMAs never wait on lgkm; one barrier/tile.
// Requires tile t+1 resident in LDS while computing tile t:
//   4-buffer LDS ring (128KB, still 1 block/CU), stage tile t+3 at tile t.
//   At top of tile t, vmcnt(4) leaves only tile t+2's 4 loads in flight =>
//   tiles <= t+1 complete; after the barrier, ALL waves' t+1 data is in LDS.
// Write-safety: staging at t writes buf (t+3)&3 = (t-1)&3; last reads of
// that buf (tile t-1 ks1 frags) are lgkm-complete before their MFMAs, which
// precede the top-of-t barrier.
// Frag sets: X = ks0 (refilled half1 from tile t+1), Y = ks1 (refilled
// half0 from tile t). Static names only (runtime-indexed reg arrays spill).
// Tail: t=62 uses vmcnt(0) (tile 63's loads are the only ones left but
// vmcnt(4) would not wait for them); staging stops at t=60 (tile 63).
// Geometry: BM=BN=256, BK=64, 8 waves 2Mx4N, wave tile 128x64 = 4x2 of
// 32x32x32 i8 MFMA. XOR chunk swizzle at global source (LDS dest linear).
// Frags: A[m=lane&31][k=(lane>>5)*16+j]; C/D col=lane&31,
// row=(reg&3)+8*(reg>>2)+4*(lane>>5)  (verified r0-r3, absmax 32).
// Epilogue: C = 7.5e-4 * (P - 32*rs[m] + 66*sy[n] - 8650752)
// ---------------------------------------------------------------------------
__global__ __launch_bounds__(512, 2) void gemm_i8(const signed char* __restrict__ A8,
                                                  const signed char* __restrict__ B8T,
                                                  const int* __restrict__ rs,
                                                  const int* __restrict__ sy,
                                                  float* __restrict__ C) {
    __shared__ __align__(16) signed char As[4 * 16384];  // 256 rows x 64B x 4
    __shared__ __align__(16) signed char Bs[4 * 16384];  // 256 rows x 64B x 4
    const int tid = threadIdx.x;
    const int lin = blockIdx.x;
    const int til = (lin & 7) * 32 + (lin >> 3);   // XCD-contiguous tiles
    const int bm = (til >> 4) * 256;
    const int bn = (til & 15) * 256;
    const int lane = tid & 63;
    const int wave = tid >> 6;
    const int wm = (wave >> 2) * 128;   // 2 m-waves x 128
    const int wn = (wave & 3) * 64;     // 4 n-waves x 64
    const int mr = lane & 31;
    const int kh = lane >> 5;

    int32x16 acc[4][2] = {};

    const int srow = tid >> 2;
    const int scol = ((tid & 3) ^ ((tid >> 3) & 3)) * 16;
    const size_t arow = (size_t)(bm + srow) * 4096 + scol;
    const size_t brow = (size_t)(bn + srow) * 4096 + scol;

    // fragment LDS offsets: row = wtile + i*32 + mr; chunk = ks*2 + kh;
    // phys slot = chunk ^ ((mr>>1)&3)
    int aoff[4][2], boff[2][2];
#pragma unroll
    for (int ks = 0; ks < 2; ks++) {
        const int slot = ((ks * 2 + kh) ^ ((mr >> 1) & 3)) * 16;
#pragma unroll
        for (int i = 0; i < 4; i++) aoff[i][ks] = (wm + i * 32 + mr) * 64 + slot;
#pragma unroll
        for (int j = 0; j < 2; j++) boff[j][ks] = (wn + j * 32 + mr) * 64 + slot;
    }

    auto stage = [&](int buf, int kt) {   // prologue: 4 gloads (2 A + 2 B)
        signed char* a_dst = As + buf * 16384 + tid * 16;
        signed char* b_dst = Bs + buf * 16384 + tid * 16;
#pragma unroll
        for (int p = 0; p < 2; p++)
            gload_lds16(A8 + arow + (size_t)p * 524288 + kt, a_dst + p * 8192);
#pragma unroll
        for (int p = 0; p < 2; p++)
            gload_lds16(B8T + brow + (size_t)p * 524288 + kt, b_dst + p * 8192);
    };

    stage(0, 0);
    stage(1, 64);
    stage(2, 128);
    // waitcnt imm: vmcnt[3:0]=bits0-3, vmcnt[5:4]=bits14-15.
    // 0xF78 = vmcnt(8), 0xF74 = vmcnt(4), 0xF70 = vmcnt(0).
    __builtin_amdgcn_s_waitcnt(0xF78);   // tile 0 landed (tiles 1,2 in flight)
    __builtin_amdgcn_s_barrier();
    __builtin_amdgcn_sched_barrier(0);

    int32x4 xa[4], xb[2];   // ks0 frags of current tile
    int32x4 ya[4], yb[2];   // ks1 frags of current tile
#pragma unroll
    for (int i = 0; i < 4; i++) xa[i] = *(const int32x4*)(As + aoff[i][0]);
#pragma unroll
    for (int j = 0; j < 2; j++) xb[j] = *(const int32x4*)(Bs + boff[j][0]);

#pragma unroll 1
    for (int t = 0; t < 64; ++t) {
        const signed char* Ab  = As + (t & 3) * 16384;        // tile t
        const signed char* Bb  = Bs + (t & 3) * 16384;
        const signed char* Abn = As + ((t + 1) & 3) * 16384;  // tile t+1
        const signed char* Bbn = Bs + ((t + 1) & 3) * 16384;
        signed char* a_dst = As + ((t + 3) & 3) * 16384 + tid * 16;
        signed char* b_dst = Bs + ((t + 3) & 3) * 16384 + tid * 16;
        const size_t gk = (size_t)(t + 3) * 64;
        const bool st = (t < 61);

        if (t == 62) __builtin_amdgcn_s_waitcnt(0xF70);  // only tile 63 left
        else         __builtin_amdgcn_s_waitcnt(0xF74);  // tiles <= t+1 done
        __builtin_amdgcn_s_barrier();
        __builtin_amdgcn_sched_barrier(0);

        // ---- half 0: refill Y <- tile t ks1; stage A of t+3; MFMA X ----
#pragma unroll
        for (int i = 0; i < 4; i++) ya[i] = *(const int32x4*)(Ab + aoff[i][1]);
#pragma unroll
        for (int j = 0; j < 2; j++) yb[j] = *(const int32x4*)(Bb + boff[j][1]);
        if (st) {
            gload_lds16(A8 + arow + gk, a_dst);
            gload_lds16(A8 + arow + 524288 + gk, a_dst + 8192);
        }
        __builtin_amdgcn_sched_barrier(0);   // reads issued before MFMAs
        __builtin_amdgcn_s_setprio(1);
        acc[0][0] = MFMA_I8(xa[0], xb[0], acc[0][0]);
        acc[0][1] = MFMA_I8(xa[0], xb[1], acc[0][1]);
        acc[1][0] = MFMA_I8(xa[1], xb[0], acc[1][0]);
        acc[1][1] = MFMA_I8(xa[1], xb[1], acc[1][1]);
        acc[2][0] = MFMA_I8(xa[2], xb[0], acc[2][0]);
        acc[2][1] = MFMA_I8(xa[2], xb[1], acc[2][1]);
        acc[3][0] = MFMA_I8(xa[3], xb[0], acc[3][0]);
        acc[3][1] = MFMA_I8(xa[3], xb[1], acc[3][1]);
        __builtin_amdgcn_s_setprio(0);

        // ---- half 1: refill X <- tile t+1 ks0; stage B of t+3; MFMA Y ----
        if (t < 63) {
#pragma unroll
            for (int i = 0; i < 4; i++) xa[i] = *(const int32x4*)(Abn + aoff[i][0]);
#pragma unroll
            for (int j = 0; j < 2; j++) xb[j] = *(const int32x4*)(Bbn + boff[j][0]);
        }
        if (st) {
            gload_lds16(B8T + brow + gk, b_dst);
            gload_lds16(B8T + brow + 524288 + gk, b_dst + 8192);
        }
        __builtin_amdgcn_sched_barrier(0);
        __builtin_amdgcn_s_setprio(1);
        acc[0][0] = MFMA_I8(ya[0], yb[0], acc[0][0]);
        acc[0][1] = MFMA_I8(ya[0], yb[1], acc[0][1]);
        acc[1][0] = MFMA_I8(ya[1], yb[0], acc[1][0]);
        acc[1][1] = MFMA_I8(ya[1], yb[1], acc[1][1]);
        acc[2][0] = MFMA_I8(ya[2], yb[0], acc[2][0]);
        acc[2][1] = MFMA_I8(ya[2], yb[1], acc[2][1]);
        acc[3][0] = MFMA_I8(ya[3], yb[0], acc[3][0]);
        acc[3][1] = MFMA_I8(ya[3], yb[1], acc[3][1]);
        __builtin_amdgcn_s_setprio(0);
    }

    // Epilogue. C/D: col = lane&31, row = (reg&3) + 8*(reg>>2) + 4*kh
#pragma unroll
    for (int i = 0; i < 4; i++) {
#pragma unroll
        for (int r = 0; r < 16; r++) {
            const int gm = bm + wm + i * 32 + (r & 3) + 8 * (r >> 2) + 4 * kh;
            const int rcorr = -32 * rs[gm] - 8650752;
#pragma unroll
            for (int j = 0; j < 2; j++) {
                const int gn = bn + wn + j * 32 + mr;
                const int v = acc[i][j][r] + rcorr + 66 * sy[gn];
                C[(size_t)gm * 4096 + gn] = 7.5e-4f * (float)v;
            }
        }
    }
}

// ---------------------------------------------------------------------------
extern "C" void kernel_launch(void* const* d_in, const int* in_sizes, int n_in,
                              void* d_out, int out_size, void* d_ws, size_t ws_size,
                              hipStream_t stream) {
    const float* x = (const float*)d_in[0];  // [4096,4096] int8-valued
    const float* y = (const float*)d_in[1];  // [4096,4096] uint8-valued
    float* out = (float*)d_out;

    char* ws = (char*)d_ws;
    signed char* A8  = (signed char*)ws;                         // 16 MiB
    signed char* B8T = (signed char*)(ws + (16u << 20));         // 16 MiB
    int* rs = (int*)(ws + (32u << 20));                          // 16 KiB
    int* sy = (int*)(ws + (32u << 20) + (16u << 10));            // 16 KiB

    hipMemsetAsync(sy, 0, 4096 * sizeof(int), stream);
    quant_xy<<<8192, 256, 0, stream>>>(x, y, A8, B8T, rs, sy);
    gemm_i8<<<256, 512, 0, stream>>>(A8, B8T, rs, sy, out);
}